// Round 1
// 353.195 us; speedup vs baseline: 1.0314x; 1.0314x over previous
//
#include <hip/hip_runtime.h>
#include <math.h>

// GAE backward scan, single fused kernel.
//   adv[t] = delta[t] + g*adv[t+1], delta[t] = r[t] + 0.99*v[t+1] - v[t], g=0.9405
// Intra-block chunked decomposition: block = 16 waves x 64 float2-columns.
// Wave w scans chunk [64w, min(64w+63,1022)] with zero carry (partials -> out),
// chunk aggregates combine through LDS, then each wave fixes up its own chunk:
//   out[t] += g^(t_hi+1-t) * K_w   (K_w = true carry into chunk w; K_15 == 0)
// 256 blocks = 1 block/CU.
// R3 theory: 8 waves/CU was latency-bound (VALUBusy 4.7%, 33% HBM, occ 19.8%).
// This round: 16 waves/CU (1024 thr, chunk=64) doubles TLP + in-flight bytes;
// phase-3 final stores are non-temporal (never re-read -> don't thrash LLC,
// keep the 268 MB of inputs resident across iterations).
// Fix-up runs FORWARD in t (most recently written partials re-read first).

#define T_OUT 1023
#define B2    16384          // 32768 floats / 2 per lane
#define NW    16             // waves (= chunks) per block
#define S_CH  64             // chunk length (last chunk: 63)

#define GAMMA_F 0.99f
#define GL_F    0.9405f      // (float)(0.99*0.95)
#define INVG_F  1.0632642212653909f   // 1/0.9405

typedef float f2v __attribute__((ext_vector_type(2)));

static __device__ __forceinline__ void nt_store_f2(float2* dst, float2 v) {
  __builtin_nontemporal_store(*(const f2v*)&v, (f2v*)dst);
}

#define STEP2(r, v)                                \
  p.x = (r).x + GAMMA_F * vn.x - (v).x + GL_F * p.x; \
  p.y = (r).y + GAMMA_F * vn.y - (v).y + GL_F * p.y;

__global__ __launch_bounds__(1024, 4) void gae_fused(
    const float2* __restrict__ r2, const float2* __restrict__ v2,
    float2* __restrict__ o2, float gS_full, float gS_last) {
  __shared__ float2 aggs[NW][64];

  const int lane = threadIdx.x & 63;
  const int w    = threadIdx.x >> 6;              // wave id == chunk id (uniform)
  const int q    = blockIdx.x * 64 + lane;        // float2 column index

  const int t_lo = w * S_CH;
  const int t_hi = (w == NW - 1) ? (T_OUT - 1) : (t_lo + S_CH - 1);

  const float2* rp = r2 + q;
  const float2* vp = v2 + q;
  float2*       op = o2 + q;

  // ---------------- phase 1: zero-carry partial scan (backward) ----------------
  float2 vn = vp[(t_hi + 1) * B2];
  float2 p  = make_float2(0.f, 0.f);

  int t = t_hi;
  const int pre = (t_hi - t_lo + 1) & 3;          // 0 for chunks 0..14, 3 for chunk 15
  for (int k = 0; k < pre; ++k, --t) {
    float2 r = rp[t * B2];
    float2 v = vp[t * B2];
    STEP2(r, v)
    op[t * B2] = p;
    vn = v;
  }

  // remaining length is a multiple of 4; software-pipelined quads
  {
    float2 rc[4], vc[4];
#pragma unroll
    for (int k = 0; k < 4; ++k) { rc[k] = rp[(t - k) * B2]; vc[k] = vp[(t - k) * B2]; }
    for (; t - 4 >= t_lo + 3; t -= 4) {
      float2 rn_[4], vn_[4];
#pragma unroll
      for (int k = 0; k < 4; ++k) { rn_[k] = rp[(t - 4 - k) * B2]; vn_[k] = vp[(t - 4 - k) * B2]; }
#pragma unroll
      for (int k = 0; k < 4; ++k) {
        STEP2(rc[k], vc[k])
        op[(t - k) * B2] = p;
        vn = vc[k];
      }
#pragma unroll
      for (int k = 0; k < 4; ++k) { rc[k] = rn_[k]; vc[k] = vn_[k]; }
    }
#pragma unroll
    for (int k = 0; k < 4; ++k) {
      STEP2(rc[k], vc[k])
      op[(t - k) * B2] = p;
      vn = vc[k];
    }
  }

  // ---------------- phase 2: combine chunk aggregates via LDS ----------------
  aggs[w][lane] = p;
  __syncthreads();

  float2 K = make_float2(0.f, 0.f);
  for (int j = NW - 1; j > w; --j) {              // wave-uniform trip count
    const float gj = (j == NW - 1) ? gS_last : gS_full;
    float2 a = aggs[j][lane];
    K.x = a.x + gj * K.x;
    K.y = a.y + gj * K.y;
  }

  // ---------------- phase 3: fix-up own chunk (forward, cache-hot first) ------
  if (w < NW - 1) {                               // chunk 15: K == 0, skip
    // x(t) = g^(t_hi+1-t) * K; at t_lo that is g^64 * K, then *= 1/g going up.
    float2 x = make_float2(gS_full * K.x, gS_full * K.y);
    int u = t_lo;                                 // len = 64, multiple of 4
    float2 oc[4];
#pragma unroll
    for (int k = 0; k < 4; ++k) oc[k] = op[(u + k) * B2];
    for (; u + 4 <= t_hi - 3; u += 4) {
      float2 on_[4];
#pragma unroll
      for (int k = 0; k < 4; ++k) on_[k] = op[(u + 4 + k) * B2];
#pragma unroll
      for (int k = 0; k < 4; ++k) {
        oc[k].x += x.x; oc[k].y += x.y;
        nt_store_f2(&op[(u + k) * B2], oc[k]);
        x.x *= INVG_F;  x.y *= INVG_F;
      }
#pragma unroll
      for (int k = 0; k < 4; ++k) oc[k] = on_[k];
    }
#pragma unroll
    for (int k = 0; k < 4; ++k) {
      oc[k].x += x.x; oc[k].y += x.y;
      nt_store_f2(&op[(u + k) * B2], oc[k]);
      x.x *= INVG_F;  x.y *= INVG_F;
    }
  }
}

extern "C" void kernel_launch(void* const* d_in, const int* in_sizes, int n_in,
                              void* d_out, int out_size, void* d_ws, size_t ws_size,
                              hipStream_t stream) {
  const float2* r2 = (const float2*)d_in[0];
  const float2* v2 = (const float2*)d_in[1];
  float2* o2 = (float2*)d_out;

  const double g = (double)GL_F;
  const float gS_full = (float)pow(g, S_CH);       // chunks 0..14 (len 64)
  const float gS_last = (float)pow(g, S_CH - 1);   // chunk 15 (63 rows)

  // 16384 float2 cols / 64 lanes = 256 blocks -> exactly 1 block (16 waves) per CU.
  gae_fused<<<dim3(B2 / 64), dim3(1024), 0, stream>>>(r2, v2, o2, gS_full, gS_last);
}

// Round 2
// 348.398 us; speedup vs baseline: 1.0456x; 1.0138x over previous
//
#include <hip/hip_runtime.h>
#include <math.h>

// GAE backward scan, single fused kernel.
//   adv[t] = delta[t] + g*adv[t+1], delta[t] = r[t] + 0.99*v[t+1] - v[t], g=0.9405
// Intra-block chunked decomposition: block = 16 waves x 64 float2-columns.
// Wave w scans chunk [64w, min(64w+63,1022)] with zero carry (partials -> out),
// chunk aggregates combine through LDS, then each wave fixes up its own chunk:
//   out[t] += g^(t_hi+1-t) * K_w   (K_w = true carry into chunk w; K_15 == 0)
// 256 blocks = 1 block/CU.
//
// R4 theory: VGPR_Count=36 proved the quad pipeline was collapsed by the
// scheduler (loads sunk below compute, buffers merged) -> every wave exposed a
// full memory round trip per quad -> lockstep convoys -> 2.9 TB/s at 38% occ.
// Fix: 4-buffer round-robin (A,B,C,D) with compile-time role alternation (NO
// rotate copies -- a prefetch register's only use is one full body later) +
// sched_barrier(0) pinning loads above compute (live ranges overlap -> the
// allocator cannot alias prefetch and compute buffers). Same treatment for
// phase 3. Expect VGPR ~80-110, BW >4 TB/s.

#define T_OUT 1023
#define B2    16384          // 32768 floats / 2 per lane
#define NW    16             // waves (= chunks) per block
#define S_CH  64             // chunk length (last chunk: 63)

#define GAMMA_F 0.99f
#define GL_F    0.9405f      // (float)(0.99*0.95)
#define INVG_F  1.0632642212653909f   // 1/0.9405

typedef float f2v __attribute__((ext_vector_type(2)));

static __device__ __forceinline__ void nt_store_f2(float2* dst, float2 v) {
  __builtin_nontemporal_store(*(const f2v*)&v, (f2v*)dst);
}

#define STEP2(r, v)                                  \
  p.x = (r).x + GAMMA_F * vn.x - (v).x + GL_F * p.x; \
  p.y = (r).y + GAMMA_F * vn.y - (v).y + GL_F * p.y;

// ---- phase-1 pipeline pieces (backward in t) ----
#define P1_LOADQ(rB_, vB_, tt)                       \
  _Pragma("unroll")                                  \
  for (int k = 0; k < 4; ++k) {                      \
    rB_[k] = rp[((tt) - k) * B2];                    \
    vB_[k] = vp[((tt) - k) * B2];                    \
  }

#define P1_COMPQ(rB_, vB_, tt)                       \
  _Pragma("unroll")                                  \
  for (int k = 0; k < 4; ++k) {                      \
    STEP2(rB_[k], vB_[k])                            \
    op[((tt) - k) * B2] = p;                         \
    vn = vB_[k];                                     \
  }

// prefetch quads (tp, tp-4) into P/Q, compute quads (tc, tc-4) from X/Y
#define P1_BODY(rP, vP, rQ, vQ, rX, vX, rY, vY)      \
  P1_LOADQ(rP, vP, tp)                               \
  P1_LOADQ(rQ, vQ, tp - 4)                           \
  __builtin_amdgcn_sched_barrier(0);                 \
  P1_COMPQ(rX, vX, tc)                               \
  P1_COMPQ(rY, vY, tc - 4)                           \
  tc -= 8; tp -= 8;

#define P1_EPI(rX, vX, rY, vY)                       \
  P1_COMPQ(rX, vX, tc)                               \
  P1_COMPQ(rY, vY, tc - 4)

// ---- phase-3 pipeline pieces (forward in t, += x with x *= 1/g per row) ----
#define P3_LOADQ(oB_, uu)                            \
  _Pragma("unroll")                                  \
  for (int k = 0; k < 4; ++k) oB_[k] = op[((uu) + k) * B2];

#define P3_COMPQ(oB_, uu)                            \
  _Pragma("unroll")                                  \
  for (int k = 0; k < 4; ++k) {                      \
    oB_[k].x += x.x; oB_[k].y += x.y;                \
    nt_store_f2(&op[((uu) + k) * B2], oB_[k]);       \
    x.x *= INVG_F; x.y *= INVG_F;                    \
  }

#define P3_BODY(oP, oQ, oX, oY)                      \
  P3_LOADQ(oP, up)                                   \
  P3_LOADQ(oQ, up + 4)                               \
  __builtin_amdgcn_sched_barrier(0);                 \
  P3_COMPQ(oX, uc)                                   \
  P3_COMPQ(oY, uc + 4)                               \
  uc += 8; up += 8;

#define P3_EPI(oX, oY)                               \
  P3_COMPQ(oX, uc)                                   \
  P3_COMPQ(oY, uc + 4)

__global__ __launch_bounds__(1024, 4) void gae_fused(
    const float2* __restrict__ r2, const float2* __restrict__ v2,
    float2* __restrict__ o2, float gS_full, float gS_last) {
  __shared__ float2 aggs[NW][64];

  const int lane = threadIdx.x & 63;
  const int w    = threadIdx.x >> 6;              // wave id == chunk id (uniform)
  const int q    = blockIdx.x * 64 + lane;        // float2 column index

  const int t_lo = w * S_CH;
  const int t_hi = (w == NW - 1) ? (T_OUT - 1) : (t_lo + S_CH - 1);

  const float2* rp = r2 + q;
  const float2* vp = v2 + q;
  float2*       op = o2 + q;

  // ---------------- phase 1: zero-carry partial scan (backward) ----------------
  float2 vn = vp[(t_hi + 1) * B2];
  float2 p  = make_float2(0.f, 0.f);

  int t = t_hi;
  if (w == NW - 1) {
    // chunk 15 has len 63; peel 7 rows (one batched round trip) so the
    // remaining 56 rows = 14 quads (even -> fits the 2-quad body pipeline).
    float2 rr[7], vv[7];
#pragma unroll
    for (int k = 0; k < 7; ++k) { rr[k] = rp[(t - k) * B2]; vv[k] = vp[(t - k) * B2]; }
#pragma unroll
    for (int k = 0; k < 7; ++k) {
      STEP2(rr[k], vv[k])
      op[(t - k) * B2] = p;
      vn = vv[k];
    }
    t -= 7;
  }

  {
    float2 rA[4], vA[4], rB[4], vB[4], rC[4], vC[4], rD[4], vD[4];
    int tc = t;            // top t of next quad pair to compute
    int tp = t - 8;        // top t of next quad pair to prefetch

    // preload first two quads
    P1_LOADQ(rA, vA, tc)
    P1_LOADQ(rB, vB, tc - 4)

    // nb bodies, each computes 2 quads + prefetches 2 quads.
    // len 64 -> nb = 7 (epilogue on C,D); len 56 -> nb = 6 (epilogue on A,B).
    const int nb = ((t - t_lo + 1) >> 3) - 1;
    int i = 0;
    for (; i + 2 <= nb; i += 2) {
      P1_BODY(rC, vC, rD, vD, rA, vA, rB, vB)
      P1_BODY(rA, vA, rB, vB, rC, vC, rD, vD)
    }
    if (i < nb) {
      P1_BODY(rC, vC, rD, vD, rA, vA, rB, vB)
      P1_EPI(rC, vC, rD, vD)
    } else {
      P1_EPI(rA, vA, rB, vB)
    }
  }

  // ---------------- phase 2: combine chunk aggregates via LDS ----------------
  aggs[w][lane] = p;
  __syncthreads();

  float2 K = make_float2(0.f, 0.f);
  for (int j = NW - 1; j > w; --j) {              // wave-uniform trip count
    const float gj = (j == NW - 1) ? gS_last : gS_full;
    float2 a = aggs[j][lane];
    K.x = a.x + gj * K.x;
    K.y = a.y + gj * K.y;
  }

  // ---------------- phase 3: fix-up own chunk (forward, cache-hot first) ------
  if (w < NW - 1) {                               // chunk 15: K == 0, skip
    // x(t) = g^(t_hi+1-t) * K; at t_lo that is g^64 * K, then *= 1/g going up.
    float2 x = make_float2(gS_full * K.x, gS_full * K.y);
    float2 oA[4], oB[4], oC[4], oD[4];
    int uc = t_lo;         // next quad pair to compute (forward)
    int up = t_lo + 8;     // next quad pair to prefetch

    P3_LOADQ(oA, uc)
    P3_LOADQ(oB, uc + 4)

    // len 64 -> 16 quads -> 7 bodies: (CD,AB) x3 + CD, epilogue on C,D.
#pragma unroll 1
    for (int i = 0; i < 3; ++i) {
      P3_BODY(oC, oD, oA, oB)
      P3_BODY(oA, oB, oC, oD)
    }
    P3_BODY(oC, oD, oA, oB)
    P3_EPI(oC, oD)
  }
}

extern "C" void kernel_launch(void* const* d_in, const int* in_sizes, int n_in,
                              void* d_out, int out_size, void* d_ws, size_t ws_size,
                              hipStream_t stream) {
  const float2* r2 = (const float2*)d_in[0];
  const float2* v2 = (const float2*)d_in[1];
  float2* o2 = (float2*)d_out;

  const double g = (double)GL_F;
  const float gS_full = (float)pow(g, S_CH);       // chunks 0..14 (len 64)
  const float gS_last = (float)pow(g, S_CH - 1);   // chunk 15 (63 rows)

  // 16384 float2 cols / 64 lanes = 256 blocks -> exactly 1 block (16 waves) per CU.
  gae_fused<<<dim3(B2 / 64), dim3(1024), 0, stream>>>(r2, v2, o2, gS_full, gS_last);
}